// Round 9
// baseline (213.587 us; speedup 1.0000x reference)
//
#include <hip/hip_runtime.h>
#include <hip/hip_fp16.h>

#define N_NODES   50000
#define N_EDGES   600000
#define N_GRAPHS  500
#define IN_DIM    64
#define D         128
#define N_CLASSES 10
#define N_PROTO   50
#define GRAPH_SZ  10
#define EPS_F     1e-4f
#define SCAN_B    256
#define NCHUNK    ((N_NODES + SCAN_B - 1) / SCAN_B)   // 196
#define NC4       (N_NODES * IN_DIM / 4)              // 800000 float4s of x
#define GEMM_TILES ((N_NODES + 63) / 64)              // 782
#define GRP8      ((N_NODES + 7) / 8)                 // 6250

typedef _Float16 half4_t __attribute__((ext_vector_type(4)));
typedef _Float16 half8_t __attribute__((ext_vector_type(8)));
typedef float    f32x4   __attribute__((ext_vector_type(4)));

struct Params {
    const float* x; const int* esrc; const int* edst; const int* bat;
    const float* W0; const float* b0; const float* W1; const float* b1;
    const float* W2; const float* b2; const float* pe; const float* lw;
    float* out;
    _Float16 *bufA, *bufB, *xs, *Bp0, *Bp1, *Bp2;
    float *pg, *dis;
    int *src_sorted, *rank, *indeg, *row_start, *bsum;
};

// ---------- pack W [K,128] fp32 -> MFMA B-fragment fp16 ----------
__device__ __forceinline__ void pack_one(const float* __restrict__ W,
                                         _Float16* __restrict__ Bp, int nks, int t) {
    int j = t & 7, l = (t >> 3) & 63;
    int rest = t >> 9;
    int s = rest % nks, c = rest / nks;
    int k = s * 32 + (l >> 4) * 8 + j;
    int col = c * 16 + (l & 15);
    Bp[t] = (_Float16)W[k * D + col];
}

// ---------- P0: zero indeg + pack weights + proto means ----------
__global__ void kw_p0(Params P) {
    int i = blockIdx.x * 256 + threadIdx.x;
    if (i < N_NODES) { P.indeg[i] = 0; return; }
    i -= N_NODES;
    if (i < 8192)  { pack_one(P.W0, P.Bp0, IN_DIM / 32, i); return; }
    i -= 8192;
    if (i < 16384) { pack_one(P.W1, P.Bp1, D / 32, i); return; }
    i -= 16384;
    if (i < 16384) { pack_one(P.W2, P.Bp2, D / 32, i); return; }
    i -= 16384;
    if (i < N_PROTO * D) {
        int p = i >> 7, j = i & 127;
        float s = 0.f;
#pragma unroll
        for (int g = 0; g < GRAPH_SZ; ++g) s += P.pe[((size_t)p * GRAPH_SZ + g) * D + j];
        P.pg[i] = s * (1.0f / GRAPH_SZ);
    }
}

// ---------- P1: count in-degrees + per-edge rank ----------
__global__ void kw_count(Params P) {
    int e = blockIdx.x * 256 + threadIdx.x;
    if (e < N_EDGES) P.rank[e] = atomicAdd(&P.indeg[P.edst[e]], 1);
}

// ---------- P2: per-chunk exclusive scan + dis ----------
__global__ void kw_scan1(Params P) {
    __shared__ int tmp[SCAN_B];
    int i = blockIdx.x * SCAN_B + threadIdx.x;
    int v = (i < N_NODES) ? P.indeg[i] : 0;
    if (i < N_NODES) P.dis[i] = rsqrtf(1.0f + (float)v);
    tmp[threadIdx.x] = v;
    __syncthreads();
    for (int off = 1; off < SCAN_B; off <<= 1) {
        int t = (threadIdx.x >= off) ? tmp[threadIdx.x - off] : 0;
        __syncthreads();
        tmp[threadIdx.x] += t;
        __syncthreads();
    }
    if (i < N_NODES) P.row_start[i] = tmp[threadIdx.x] - v;
    if (threadIdx.x == SCAN_B - 1) P.bsum[blockIdx.x] = tmp[threadIdx.x];
}

// ---------- P3: add chunk prefix ----------
__global__ void kw_scan23(Params P) {
    __shared__ int red[4];
    int c = blockIdx.x;
    int v = 0;
    for (int i = threadIdx.x; i < c; i += SCAN_B) v += P.bsum[i];
#pragma unroll
    for (int off = 32; off; off >>= 1) v += __shfl_down(v, off);
    if ((threadIdx.x & 63) == 0) red[threadIdx.x >> 6] = v;
    __syncthreads();
    int spre = red[0] + red[1] + red[2] + red[3];
    int i = c * SCAN_B + threadIdx.x;
    if (i < N_NODES) P.row_start[i] += spre;
    if (i == 0) P.row_start[N_NODES] = N_EDGES;
}

// ---------- P4: CSR fill (atomic-free) + x -> xs = dis*x fp16 ----------
__global__ void kw_fillconv(Params P) {
    int t = blockIdx.x * 256 + threadIdx.x;
    if (t < N_EDGES) {
        int d = P.edst[t];
        P.src_sorted[P.row_start[d] + P.rank[t]] = P.esrc[t];
    } else if (t < N_EDGES + NC4) {
        int i = t - N_EDGES;
        float4 v = ((const float4*)P.x)[i];
        float dd = P.dis[i >> 4];           // 16 float4s per 64-dim node
        half4_t h = { (_Float16)(v.x * dd), (_Float16)(v.y * dd),
                      (_Float16)(v.z * dd), (_Float16)(v.w * dd) };
        ((half4_t*)P.xs)[i] = h;
    }
}

// ---------- P5: fused agg(x) -> GEMM0 -> relu+b0 -> GEMM1 -> bufB ----------
__global__ __launch_bounds__(256) void kw_gemm01(Params P) {
    __shared__ _Float16 xs_t[64][72];     // 64-dim agg rows, +8 pad
    __shared__ _Float16 h1_t[64][136];    // 128-dim h1 rows, +8 pad
    int tid = threadIdx.x;
    int row0 = blockIdx.x * 64;

    // phase0: aggregate xs rows for this block's 64 nodes into LDS
    {
        int grp = tid >> 5, lane16 = tid & 15, hf = (tid >> 4) & 1;
        int j4 = lane16 * 4;
        for (int iter = 0; iter < 8; ++iter) {
            int nrel = iter * 8 + grp;
            int node = row0 + nrel;
            float a0 = 0.f, a1 = 0.f, a2 = 0.f, a3 = 0.f;
            if (node < N_NODES) {
                int s0 = P.row_start[node], s1 = P.row_start[node + 1];
                for (int k = s0 + hf; k < s1; k += 2) {
                    int s = P.src_sorted[k];
                    half4_t v = *(const half4_t*)&P.xs[(size_t)s * IN_DIM + j4];
                    a0 += (float)v[0]; a1 += (float)v[1];
                    a2 += (float)v[2]; a3 += (float)v[3];
                }
            }
            a0 += __shfl_xor(a0, 16); a1 += __shfl_xor(a1, 16);
            a2 += __shfl_xor(a2, 16); a3 += __shfl_xor(a3, 16);
            if (hf == 0) {
                half4_t r = { (_Float16)0.f, (_Float16)0.f, (_Float16)0.f, (_Float16)0.f };
                if (node < N_NODES) {
                    half4_t hv = *(const half4_t*)&P.xs[(size_t)node * IN_DIM + j4];
                    float dd = P.dis[node];
                    r[0] = (_Float16)((a0 + (float)hv[0]) * dd);
                    r[1] = (_Float16)((a1 + (float)hv[1]) * dd);
                    r[2] = (_Float16)((a2 + (float)hv[2]) * dd);
                    r[3] = (_Float16)((a3 + (float)hv[3]) * dd);
                }
                *(half4_t*)&xs_t[nrel][j4] = r;
            }
        }
    }
    __syncthreads();

    int wave = tid >> 6, lane = tid & 63;
    int l15 = lane & 15;
    int kof = (lane >> 4) * 8;
    int rb  = (lane >> 4) * 4;

    // phase1: GEMM0 (K=64), epilogue relu(+b0) -> h1_t
    {
        half8_t af0 = *(const half8_t*)&xs_t[wave * 16 + l15][kof];
        half8_t af1 = *(const half8_t*)&xs_t[wave * 16 + l15][32 + kof];
        f32x4 acc[8];
#pragma unroll
        for (int c = 0; c < 8; ++c) acc[c] = (f32x4){0.f, 0.f, 0.f, 0.f};
#pragma unroll
        for (int c = 0; c < 8; ++c) {
            half8_t b0f = *(const half8_t*)&P.Bp0[(size_t)((c * 2 + 0) * 64 + lane) * 8];
            half8_t b1f = *(const half8_t*)&P.Bp0[(size_t)((c * 2 + 1) * 64 + lane) * 8];
            acc[c] = __builtin_amdgcn_mfma_f32_16x16x32_f16(af0, b0f, acc[c], 0, 0, 0);
            acc[c] = __builtin_amdgcn_mfma_f32_16x16x32_f16(af1, b1f, acc[c], 0, 0, 0);
        }
#pragma unroll
        for (int c = 0; c < 8; ++c) {
            float bv = P.b0[c * 16 + l15];
#pragma unroll
            for (int r = 0; r < 4; ++r)
                h1_t[wave * 16 + rb + r][c * 16 + l15] = (_Float16)fmaxf(acc[c][r] + bv, 0.f);
        }
    }
    __syncthreads();

    // phase2: GEMM1 (K=128), epilogue *dis -> bufB (= hs1)
    {
        half8_t af[4];
#pragma unroll
        for (int s = 0; s < 4; ++s)
            af[s] = *(const half8_t*)&h1_t[wave * 16 + l15][s * 32 + kof];
        f32x4 acc[8];
#pragma unroll
        for (int c = 0; c < 8; ++c) acc[c] = (f32x4){0.f, 0.f, 0.f, 0.f};
#pragma unroll
        for (int c = 0; c < 8; ++c) {
#pragma unroll
            for (int s = 0; s < 4; ++s) {
                half8_t bf = *(const half8_t*)&P.Bp1[(size_t)((c * 4 + s) * 64 + lane) * 8];
                acc[c] = __builtin_amdgcn_mfma_f32_16x16x32_f16(af[s], bf, acc[c], 0, 0, 0);
            }
        }
        float dsc[4];
#pragma unroll
        for (int r = 0; r < 4; ++r) {
            int row = row0 + wave * 16 + rb + r;
            dsc[r] = (row < N_NODES) ? P.dis[row] : 0.f;
        }
#pragma unroll
        for (int c = 0; c < 8; ++c) {
#pragma unroll
            for (int r = 0; r < 4; ++r) {
                int row = row0 + wave * 16 + rb + r;
                if (row < N_NODES)
                    P.bufB[(size_t)row * D + c * 16 + l15] = (_Float16)(acc[c][r] * dsc[r]);
            }
        }
    }
}

// ---------- P6: fused gather(h2) -> GEMM2 -> bufA (= hs2) ----------
__global__ __launch_bounds__(256) void kw_gathergemm2(Params P) {
    __shared__ _Float16 h2_t[64][136];
    int tid = threadIdx.x;
    int row0 = blockIdx.x * 64;

    // phase0: h2 = relu(dis*(sum bufB[src] + bufB[self]) + b1) -> LDS
    {
        int grp = tid >> 5, lane16 = tid & 15, hf = (tid >> 4) & 1;
        int j8 = lane16 * 8;
        for (int iter = 0; iter < 8; ++iter) {
            int nrel = iter * 8 + grp;
            int node = row0 + nrel;
            float a[8] = {0.f, 0.f, 0.f, 0.f, 0.f, 0.f, 0.f, 0.f};
            if (node < N_NODES) {
                int s0 = P.row_start[node], s1 = P.row_start[node + 1];
                for (int k = s0 + hf; k < s1; k += 2) {
                    int s = P.src_sorted[k];
                    half8_t v = *(const half8_t*)&P.bufB[(size_t)s * D + j8];
#pragma unroll
                    for (int j = 0; j < 8; ++j) a[j] += (float)v[j];
                }
            }
#pragma unroll
            for (int j = 0; j < 8; ++j) a[j] += __shfl_xor(a[j], 16);
            if (hf == 0) {
                half8_t r = { (_Float16)0.f, (_Float16)0.f, (_Float16)0.f, (_Float16)0.f,
                              (_Float16)0.f, (_Float16)0.f, (_Float16)0.f, (_Float16)0.f };
                if (node < N_NODES) {
                    float dd = P.dis[node];
                    half8_t hv = *(const half8_t*)&P.bufB[(size_t)node * D + j8];
#pragma unroll
                    for (int j = 0; j < 8; ++j)
                        r[j] = (_Float16)fmaxf((a[j] + (float)hv[j]) * dd + P.b1[j8 + j], 0.f);
                }
                *(half8_t*)&h2_t[nrel][j8] = r;
            }
        }
    }
    __syncthreads();

    // phase1: GEMM2 (K=128), epilogue *dis -> bufA (= hs2)
    int wave = tid >> 6, lane = tid & 63;
    int l15 = lane & 15;
    int kof = (lane >> 4) * 8;
    int rb  = (lane >> 4) * 4;
    {
        half8_t af[4];
#pragma unroll
        for (int s = 0; s < 4; ++s)
            af[s] = *(const half8_t*)&h2_t[wave * 16 + l15][s * 32 + kof];
        f32x4 acc[8];
#pragma unroll
        for (int c = 0; c < 8; ++c) acc[c] = (f32x4){0.f, 0.f, 0.f, 0.f};
#pragma unroll
        for (int c = 0; c < 8; ++c) {
#pragma unroll
            for (int s = 0; s < 4; ++s) {
                half8_t bf = *(const half8_t*)&P.Bp2[(size_t)((c * 4 + s) * 64 + lane) * 8];
                acc[c] = __builtin_amdgcn_mfma_f32_16x16x32_f16(af[s], bf, acc[c], 0, 0, 0);
            }
        }
        float dsc[4];
#pragma unroll
        for (int r = 0; r < 4; ++r) {
            int row = row0 + wave * 16 + rb + r;
            dsc[r] = (row < N_NODES) ? P.dis[row] : 0.f;
        }
#pragma unroll
        for (int c = 0; c < 8; ++c) {
#pragma unroll
            for (int r = 0; r < 4; ++r) {
                int row = row0 + wave * 16 + rb + r;
                if (row < N_NODES)
                    P.bufA[(size_t)row * D + c * 16 + l15] = (_Float16)(acc[c][r] * dsc[r]);
            }
        }
    }
}

// ---------- P7: final gather: h3 = relu(dis*(sum bufA[src]+self)+b2) -> bufB ----------
__global__ void kw_gather2(Params P) {
    int node = blockIdx.x * 8 + (threadIdx.x >> 5);
    if (node >= N_NODES) return;
    int lane16 = threadIdx.x & 15;
    int hf = (threadIdx.x >> 4) & 1;
    int j8 = lane16 * 8;
    int s0 = P.row_start[node], s1 = P.row_start[node + 1];
    float a[8] = {0.f, 0.f, 0.f, 0.f, 0.f, 0.f, 0.f, 0.f};
    for (int k = s0 + hf; k < s1; k += 2) {
        int s = P.src_sorted[k];
        half8_t v = *(const half8_t*)&P.bufA[(size_t)s * D + j8];
#pragma unroll
        for (int j = 0; j < 8; ++j) a[j] += (float)v[j];
    }
#pragma unroll
    for (int j = 0; j < 8; ++j) a[j] += __shfl_xor(a[j], 16);
    if (hf == 0) {
        float dd = P.dis[node];
        half8_t hv = *(const half8_t*)&P.bufA[(size_t)node * D + j8];
        half8_t r;
#pragma unroll
        for (int j = 0; j < 8; ++j)
            r[j] = (_Float16)fmaxf((a[j] + (float)hv[j]) * dd + P.b2[j8 + j], 0.f);
        *(half8_t*)&P.bufB[(size_t)node * D + j8] = r;
    }
}

// ---------- P8: readout + sim + logits (512 threads / graph) ----------
__global__ void kw_readout(Params P) {
    __shared__ int sh[2];
    __shared__ float red[4][D];
    __shared__ float gs[D];
    __shared__ float sim[N_PROTO];
    const _Float16* h = P.bufB;
    int g = blockIdx.x;
    if (threadIdx.x == 0) {
        int lo = 0, hi = N_NODES;
        while (lo < hi) { int m = (lo + hi) >> 1; if (P.bat[m] < g) lo = m + 1; else hi = m; }
        sh[0] = lo;
        hi = N_NODES;
        while (lo < hi) { int m = (lo + hi) >> 1; if (P.bat[m] < g + 1) lo = m + 1; else hi = m; }
        sh[1] = lo;
    }
    __syncthreads();
    int s0 = sh[0], s1 = sh[1];
    int col = threadIdx.x & 127;
    int part = threadIdx.x >> 7;          // 0..3
    float sum = 0.f;
    for (int n = s0 + part; n < s1; n += 4) sum += (float)h[(size_t)n * D + col];
    red[part][col] = sum;
    __syncthreads();
    if (part == 0)
        gs[col] = (sum + red[1][col] + red[2][col] + red[3][col])
                  / fmaxf((float)(s1 - s0), 1.0f);
    __syncthreads();
    int t = threadIdx.x;
    if (t < N_PROTO * 8) {                // 8 threads per proto
        int p = t >> 3, sub = t & 7;
        const float* q = P.pg + (size_t)p * D;
        float d2 = 0.f;
        int j0 = sub * 16;
#pragma unroll
        for (int j = 0; j < 16; ++j) {
            float df = gs[j0 + j] - q[j0 + j];
            d2 = fmaf(df, df, d2);
        }
        d2 += __shfl_xor(d2, 1);
        d2 += __shfl_xor(d2, 2);
        d2 += __shfl_xor(d2, 4);
        if (sub == 0) sim[p] = logf((d2 + 1.0f) / (d2 + EPS_F));
    }
    __syncthreads();
    if (t < N_CLASSES) {
        float s = 0.f;
#pragma unroll
        for (int p = 0; p < N_PROTO; ++p) s = fmaf(sim[p], P.lw[t * N_PROTO + p], s);
        P.out[(size_t)g * N_CLASSES + t] = s;
    }
}

extern "C" void kernel_launch(void* const* d_in, const int* in_sizes, int n_in,
                              void* d_out, int out_size, void* d_ws, size_t ws_size,
                              hipStream_t stream) {
    Params P;
    P.x    = (const float*)d_in[0];
    P.esrc = (const int*)d_in[1];
    P.edst = (const int*)d_in[1] + N_EDGES;
    P.bat  = (const int*)d_in[2];
    P.W0 = (const float*)d_in[3];  P.b0 = (const float*)d_in[4];
    P.W1 = (const float*)d_in[5];  P.b1 = (const float*)d_in[6];
    P.W2 = (const float*)d_in[7];  P.b2 = (const float*)d_in[8];
    P.pe = (const float*)d_in[9];  P.lw = (const float*)d_in[10];
    P.out = (float*)d_out;

    char* wsb = (char*)d_ws;
    P.bufA = (_Float16*)wsb;  wsb += (size_t)N_NODES * D * 2;
    P.bufB = (_Float16*)wsb;  wsb += (size_t)N_NODES * D * 2;
    P.xs   = (_Float16*)wsb;  wsb += (size_t)N_NODES * IN_DIM * 2;
    P.Bp0  = (_Float16*)wsb;  wsb += (size_t)IN_DIM * D * 2;
    P.Bp1  = (_Float16*)wsb;  wsb += (size_t)D * D * 2;
    P.Bp2  = (_Float16*)wsb;  wsb += (size_t)D * D * 2;
    P.pg   = (float*)wsb;     wsb += (size_t)N_PROTO * D * 4;
    P.dis  = (float*)wsb;     wsb += (size_t)N_NODES * 4;
    P.src_sorted = (int*)wsb; wsb += (size_t)N_EDGES * 4;
    P.rank       = (int*)wsb; wsb += (size_t)N_EDGES * 4;
    P.indeg      = (int*)wsb; wsb += (size_t)N_NODES * 4;
    P.row_start  = (int*)wsb; wsb += (size_t)(N_NODES + 2) * 4;
    P.bsum       = (int*)wsb; wsb += (size_t)NCHUNK * 4;

    const int TB = 256;
    int e_blocks  = (N_EDGES + TB - 1) / TB;
    int p0_blocks = (N_NODES + 8192 + 16384 + 16384 + N_PROTO * D + TB - 1) / TB;
    int fc_blocks = (N_EDGES + NC4 + TB - 1) / TB;

    kw_p0<<<p0_blocks, TB, 0, stream>>>(P);
    kw_count<<<e_blocks, TB, 0, stream>>>(P);
    kw_scan1<<<NCHUNK, SCAN_B, 0, stream>>>(P);
    kw_scan23<<<NCHUNK, SCAN_B, 0, stream>>>(P);
    kw_fillconv<<<fc_blocks, TB, 0, stream>>>(P);
    kw_gemm01<<<GEMM_TILES, TB, 0, stream>>>(P);
    kw_gathergemm2<<<GEMM_TILES, TB, 0, stream>>>(P);
    kw_gather2<<<GRP8, TB, 0, stream>>>(P);
    kw_readout<<<N_GRAPHS, 512, 0, stream>>>(P);
}

// Round 10
// 186.313 us; speedup vs baseline: 1.1464x; 1.1464x over previous
//
#include <hip/hip_runtime.h>
#include <hip/hip_fp16.h>

#define N_NODES   50000
#define N_EDGES   600000
#define N_GRAPHS  500
#define IN_DIM    64
#define D         128
#define N_CLASSES 10
#define N_PROTO   50
#define GRAPH_SZ  10
#define EPS_F     1e-4f
#define SCAN_B    256
#define NCHUNK    ((N_NODES + SCAN_B - 1) / SCAN_B)   // 196
#define NC4       (N_NODES * IN_DIM / 4)              // 800000 float4s of x
#define GEMM_TILES ((N_NODES + 63) / 64)              // 782
#define GRP8      ((N_NODES + 7) / 8)                 // 6250

typedef _Float16 half4_t __attribute__((ext_vector_type(4)));
typedef _Float16 half8_t __attribute__((ext_vector_type(8)));
typedef float    f32x4   __attribute__((ext_vector_type(4)));

struct Params {
    const float* x; const int* esrc; const int* edst; const int* bat;
    const float* W0; const float* b0; const float* W1; const float* b1;
    const float* W2; const float* b2; const float* pe; const float* lw;
    float* out;
    _Float16 *bufA, *bufB, *xs, *agg0, *Bp0, *Bp1, *Bp2;
    float *pg, *dis;
    int *src_sorted, *rank, *indeg, *row_start, *bsum;
};

// ---------- pack W [K,128] fp32 -> MFMA B-fragment fp16 ----------
__device__ __forceinline__ void pack_one(const float* __restrict__ W,
                                         _Float16* __restrict__ Bp, int nks, int t) {
    int j = t & 7, l = (t >> 3) & 63;
    int rest = t >> 9;
    int s = rest % nks, c = rest / nks;
    int k = s * 32 + (l >> 4) * 8 + j;
    int col = c * 16 + (l & 15);
    Bp[t] = (_Float16)W[k * D + col];
}

// ---------- P0: zero indeg + pack weights + proto means ----------
__global__ void kw_p0(Params P) {
    int i = blockIdx.x * 256 + threadIdx.x;
    if (i < N_NODES) { P.indeg[i] = 0; return; }
    i -= N_NODES;
    if (i < 8192)  { pack_one(P.W0, P.Bp0, IN_DIM / 32, i); return; }
    i -= 8192;
    if (i < 16384) { pack_one(P.W1, P.Bp1, D / 32, i); return; }
    i -= 16384;
    if (i < 16384) { pack_one(P.W2, P.Bp2, D / 32, i); return; }
    i -= 16384;
    if (i < N_PROTO * D) {
        int p = i >> 7, j = i & 127;
        float s = 0.f;
#pragma unroll
        for (int g = 0; g < GRAPH_SZ; ++g) s += P.pe[((size_t)p * GRAPH_SZ + g) * D + j];
        P.pg[i] = s * (1.0f / GRAPH_SZ);
    }
}

// ---------- P1: count in-degrees + per-edge rank ----------
__global__ void kw_count(Params P) {
    int e = blockIdx.x * 256 + threadIdx.x;
    if (e < N_EDGES) P.rank[e] = atomicAdd(&P.indeg[P.edst[e]], 1);
}

// ---------- P2: per-chunk exclusive scan + dis ----------
__global__ void kw_scan1(Params P) {
    __shared__ int tmp[SCAN_B];
    int i = blockIdx.x * SCAN_B + threadIdx.x;
    int v = (i < N_NODES) ? P.indeg[i] : 0;
    if (i < N_NODES) P.dis[i] = rsqrtf(1.0f + (float)v);
    tmp[threadIdx.x] = v;
    __syncthreads();
    for (int off = 1; off < SCAN_B; off <<= 1) {
        int t = (threadIdx.x >= off) ? tmp[threadIdx.x - off] : 0;
        __syncthreads();
        tmp[threadIdx.x] += t;
        __syncthreads();
    }
    if (i < N_NODES) P.row_start[i] = tmp[threadIdx.x] - v;
    if (threadIdx.x == SCAN_B - 1) P.bsum[blockIdx.x] = tmp[threadIdx.x];
}

// ---------- P3: add chunk prefix ----------
__global__ void kw_scan23(Params P) {
    __shared__ int red[4];
    int c = blockIdx.x;
    int v = 0;
    for (int i = threadIdx.x; i < c; i += SCAN_B) v += P.bsum[i];
#pragma unroll
    for (int off = 32; off; off >>= 1) v += __shfl_down(v, off);
    if ((threadIdx.x & 63) == 0) red[threadIdx.x >> 6] = v;
    __syncthreads();
    int spre = red[0] + red[1] + red[2] + red[3];
    int i = c * SCAN_B + threadIdx.x;
    if (i < N_NODES) P.row_start[i] += spre;
    if (i == 0) P.row_start[N_NODES] = N_EDGES;
}

// ---------- P4: CSR fill (atomic-free) + x -> xs = dis*x fp16 ----------
__global__ void kw_fillconv(Params P) {
    int t = blockIdx.x * 256 + threadIdx.x;
    if (t < N_EDGES) {
        int d = P.edst[t];
        P.src_sorted[P.row_start[d] + P.rank[t]] = P.esrc[t];
    } else if (t < N_EDGES + NC4) {
        int i = t - N_EDGES;
        float4 v = ((const float4*)P.x)[i];
        float dd = P.dis[i >> 4];           // 16 float4s per 64-dim node
        half4_t h = { (_Float16)(v.x * dd), (_Float16)(v.y * dd),
                      (_Float16)(v.z * dd), (_Float16)(v.w * dd) };
        ((half4_t*)P.xs)[i] = h;
    }
}

// ---------- P5: 64-dim aggregation: agg0 = dis[d]*(sum xs[src] + xs[d]) ----------
__global__ void kw_agg64(Params P) {
    int node = blockIdx.x * 8 + (threadIdx.x >> 5);
    if (node >= N_NODES) return;
    int lane16 = threadIdx.x & 15;
    int hf = (threadIdx.x >> 4) & 1;
    int j4 = lane16 * 4;
    int s0 = P.row_start[node], s1 = P.row_start[node + 1];
    float a0 = 0.f, a1 = 0.f, a2 = 0.f, a3 = 0.f;
    for (int k = s0 + hf; k < s1; k += 2) {
        int s = P.src_sorted[k];
        half4_t v = *(const half4_t*)&P.xs[(size_t)s * IN_DIM + j4];
        a0 += (float)v[0]; a1 += (float)v[1]; a2 += (float)v[2]; a3 += (float)v[3];
    }
    a0 += __shfl_xor(a0, 16);
    a1 += __shfl_xor(a1, 16);
    a2 += __shfl_xor(a2, 16);
    a3 += __shfl_xor(a3, 16);
    if (hf == 0) {
        half4_t hv = *(const half4_t*)&P.xs[(size_t)node * IN_DIM + j4];
        float dd = P.dis[node];
        half4_t r = { (_Float16)((a0 + (float)hv[0]) * dd),
                      (_Float16)((a1 + (float)hv[1]) * dd),
                      (_Float16)((a2 + (float)hv[2]) * dd),
                      (_Float16)((a3 + (float)hv[3]) * dd) };
        *(half4_t*)&P.agg0[(size_t)node * IN_DIM + j4] = r;
    }
}

// ---------- P6: fused GEMM0(relu+b0) -> LDS transpose -> GEMM1(*dis) ----------
__global__ __launch_bounds__(256) void kw_gemm01(Params P) {
    __shared__ _Float16 h1_t[64][136];    // 128-dim h1 rows, +8 pad
    int tid = threadIdx.x;
    int row0 = blockIdx.x * 64;
    int wave = tid >> 6, lane = tid & 63;
    int l15 = lane & 15;
    int kof = (lane >> 4) * 8;
    int rb  = (lane >> 4) * 4;

    // phase1: GEMM0 (K=64) from global agg0, epilogue relu(+b0) -> h1_t
    {
        int arow = row0 + wave * 16 + l15;
        if (arow >= N_NODES) arow = N_NODES - 1;
        const _Float16* ap = P.agg0 + (size_t)arow * IN_DIM;
        half8_t af0 = *(const half8_t*)(ap + kof);
        half8_t af1 = *(const half8_t*)(ap + 32 + kof);
        f32x4 acc[8];
#pragma unroll
        for (int c = 0; c < 8; ++c) acc[c] = (f32x4){0.f, 0.f, 0.f, 0.f};
#pragma unroll
        for (int c = 0; c < 8; ++c) {
            half8_t b0f = *(const half8_t*)&P.Bp0[(size_t)((c * 2 + 0) * 64 + lane) * 8];
            half8_t b1f = *(const half8_t*)&P.Bp0[(size_t)((c * 2 + 1) * 64 + lane) * 8];
            acc[c] = __builtin_amdgcn_mfma_f32_16x16x32_f16(af0, b0f, acc[c], 0, 0, 0);
            acc[c] = __builtin_amdgcn_mfma_f32_16x16x32_f16(af1, b1f, acc[c], 0, 0, 0);
        }
#pragma unroll
        for (int c = 0; c < 8; ++c) {
            float bv = P.b0[c * 16 + l15];
#pragma unroll
            for (int r = 0; r < 4; ++r)
                h1_t[wave * 16 + rb + r][c * 16 + l15] = (_Float16)fmaxf(acc[c][r] + bv, 0.f);
        }
    }
    __syncthreads();

    // phase2: GEMM1 (K=128) from h1_t, epilogue *dis -> bufA (= hs1)
    {
        half8_t af[4];
#pragma unroll
        for (int s = 0; s < 4; ++s)
            af[s] = *(const half8_t*)&h1_t[wave * 16 + l15][s * 32 + kof];
        f32x4 acc[8];
#pragma unroll
        for (int c = 0; c < 8; ++c) acc[c] = (f32x4){0.f, 0.f, 0.f, 0.f};
#pragma unroll
        for (int c = 0; c < 8; ++c) {
#pragma unroll
            for (int s = 0; s < 4; ++s) {
                half8_t bf = *(const half8_t*)&P.Bp1[(size_t)((c * 4 + s) * 64 + lane) * 8];
                acc[c] = __builtin_amdgcn_mfma_f32_16x16x32_f16(af[s], bf, acc[c], 0, 0, 0);
            }
        }
        float dsc[4];
#pragma unroll
        for (int r = 0; r < 4; ++r) {
            int row = row0 + wave * 16 + rb + r;
            dsc[r] = (row < N_NODES) ? P.dis[row] : 0.f;
        }
#pragma unroll
        for (int c = 0; c < 8; ++c) {
#pragma unroll
            for (int r = 0; r < 4; ++r) {
                int row = row0 + wave * 16 + rb + r;
                if (row < N_NODES)
                    P.bufA[(size_t)row * D + c * 16 + l15] = (_Float16)(acc[c][r] * dsc[r]);
            }
        }
    }
}

// ---------- 128-dim gather: hout = relu(dis[d]*(sum hin[src] + hin[d]) + b) ----------
__device__ void gather_body(const Params& P, const _Float16* __restrict__ hin,
                            const float* __restrict__ bias, _Float16* __restrict__ hout) {
    int node = blockIdx.x * 8 + (threadIdx.x >> 5);
    if (node >= N_NODES) return;
    int lane16 = threadIdx.x & 15;
    int hf = (threadIdx.x >> 4) & 1;
    int j8 = lane16 * 8;
    int s0 = P.row_start[node], s1 = P.row_start[node + 1];
    float a[8] = {0.f, 0.f, 0.f, 0.f, 0.f, 0.f, 0.f, 0.f};
    for (int k = s0 + hf; k < s1; k += 2) {
        int s = P.src_sorted[k];
        half8_t v = *(const half8_t*)&hin[(size_t)s * D + j8];
#pragma unroll
        for (int j = 0; j < 8; ++j) a[j] += (float)v[j];
    }
#pragma unroll
    for (int j = 0; j < 8; ++j) a[j] += __shfl_xor(a[j], 16);
    if (hf == 0) {
        float dd = P.dis[node];
        half8_t hv = *(const half8_t*)&hin[(size_t)node * D + j8];
        half8_t r;
#pragma unroll
        for (int j = 0; j < 8; ++j)
            r[j] = (_Float16)fmaxf((a[j] + (float)hv[j]) * dd + bias[j8 + j], 0.f);
        *(half8_t*)&hout[(size_t)node * D + j8] = r;
    }
}

__global__ void kw_gather1(Params P) { gather_body(P, P.bufA, P.b1, P.bufB); }
__global__ void kw_gather2(Params P) { gather_body(P, P.bufA, P.b2, P.bufB); }

// ---------- P8: GEMM2 (K=128): bufB(h2) @ W2 *dis -> bufA (= hs2) ----------
__global__ __launch_bounds__(256) void kw_gemm2(Params P) {
    int tid = threadIdx.x;
    int row0 = blockIdx.x * 64;
    int wave = tid >> 6, lane = tid & 63;
    int l15 = lane & 15;
    int kof = (lane >> 4) * 8;
    int rb  = (lane >> 4) * 4;
    int arow = row0 + wave * 16 + l15;
    if (arow >= N_NODES) arow = N_NODES - 1;
    const _Float16* ap = P.bufB + (size_t)arow * D;
    half8_t af[4];
#pragma unroll
    for (int s = 0; s < 4; ++s) af[s] = *(const half8_t*)(ap + s * 32 + kof);
    f32x4 acc[8];
#pragma unroll
    for (int c = 0; c < 8; ++c) acc[c] = (f32x4){0.f, 0.f, 0.f, 0.f};
#pragma unroll
    for (int c = 0; c < 8; ++c) {
#pragma unroll
        for (int s = 0; s < 4; ++s) {
            half8_t bf = *(const half8_t*)&P.Bp2[(size_t)((c * 4 + s) * 64 + lane) * 8];
            acc[c] = __builtin_amdgcn_mfma_f32_16x16x32_f16(af[s], bf, acc[c], 0, 0, 0);
        }
    }
    float dsc[4];
#pragma unroll
    for (int r = 0; r < 4; ++r) {
        int row = row0 + wave * 16 + rb + r;
        dsc[r] = (row < N_NODES) ? P.dis[row] : 0.f;
    }
#pragma unroll
    for (int c = 0; c < 8; ++c) {
#pragma unroll
        for (int r = 0; r < 4; ++r) {
            int row = row0 + wave * 16 + rb + r;
            if (row < N_NODES)
                P.bufA[(size_t)row * D + c * 16 + l15] = (_Float16)(acc[c][r] * dsc[r]);
        }
    }
}

// ---------- P10: readout + sim + logits (512 threads / graph) ----------
__global__ void kw_readout(Params P) {
    __shared__ int sh[2];
    __shared__ float red[4][D];
    __shared__ float gs[D];
    __shared__ float sim[N_PROTO];
    const _Float16* h = P.bufB;
    int g = blockIdx.x;
    if (threadIdx.x == 0) {
        int lo = 0, hi = N_NODES;
        while (lo < hi) { int m = (lo + hi) >> 1; if (P.bat[m] < g) lo = m + 1; else hi = m; }
        sh[0] = lo;
        hi = N_NODES;
        while (lo < hi) { int m = (lo + hi) >> 1; if (P.bat[m] < g + 1) lo = m + 1; else hi = m; }
        sh[1] = lo;
    }
    __syncthreads();
    int s0 = sh[0], s1 = sh[1];
    int col = threadIdx.x & 127;
    int part = threadIdx.x >> 7;          // 0..3
    float sum = 0.f;
    for (int n = s0 + part; n < s1; n += 4) sum += (float)h[(size_t)n * D + col];
    red[part][col] = sum;
    __syncthreads();
    if (part == 0)
        gs[col] = (sum + red[1][col] + red[2][col] + red[3][col])
                  / fmaxf((float)(s1 - s0), 1.0f);
    __syncthreads();
    int t = threadIdx.x;
    if (t < N_PROTO * 8) {                // 8 threads per proto
        int p = t >> 3, sub = t & 7;
        const float* q = P.pg + (size_t)p * D;
        float d2 = 0.f;
        int j0 = sub * 16;
#pragma unroll
        for (int j = 0; j < 16; ++j) {
            float df = gs[j0 + j] - q[j0 + j];
            d2 = fmaf(df, df, d2);
        }
        d2 += __shfl_xor(d2, 1);
        d2 += __shfl_xor(d2, 2);
        d2 += __shfl_xor(d2, 4);
        if (sub == 0) sim[p] = logf((d2 + 1.0f) / (d2 + EPS_F));
    }
    __syncthreads();
    if (t < N_CLASSES) {
        float s = 0.f;
#pragma unroll
        for (int p = 0; p < N_PROTO; ++p) s = fmaf(sim[p], P.lw[t * N_PROTO + p], s);
        P.out[(size_t)g * N_CLASSES + t] = s;
    }
}

extern "C" void kernel_launch(void* const* d_in, const int* in_sizes, int n_in,
                              void* d_out, int out_size, void* d_ws, size_t ws_size,
                              hipStream_t stream) {
    Params P;
    P.x    = (const float*)d_in[0];
    P.esrc = (const int*)d_in[1];
    P.edst = (const int*)d_in[1] + N_EDGES;
    P.bat  = (const int*)d_in[2];
    P.W0 = (const float*)d_in[3];  P.b0 = (const float*)d_in[4];
    P.W1 = (const float*)d_in[5];  P.b1 = (const float*)d_in[6];
    P.W2 = (const float*)d_in[7];  P.b2 = (const float*)d_in[8];
    P.pe = (const float*)d_in[9];  P.lw = (const float*)d_in[10];
    P.out = (float*)d_out;

    char* wsb = (char*)d_ws;
    P.bufA = (_Float16*)wsb;  wsb += (size_t)N_NODES * D * 2;
    P.bufB = (_Float16*)wsb;  wsb += (size_t)N_NODES * D * 2;
    P.xs   = (_Float16*)wsb;  wsb += (size_t)N_NODES * IN_DIM * 2;
    P.agg0 = (_Float16*)wsb;  wsb += (size_t)N_NODES * IN_DIM * 2;
    P.Bp0  = (_Float16*)wsb;  wsb += (size_t)IN_DIM * D * 2;
    P.Bp1  = (_Float16*)wsb;  wsb += (size_t)D * D * 2;
    P.Bp2  = (_Float16*)wsb;  wsb += (size_t)D * D * 2;
    P.pg   = (float*)wsb;     wsb += (size_t)N_PROTO * D * 4;
    P.dis  = (float*)wsb;     wsb += (size_t)N_NODES * 4;
    P.src_sorted = (int*)wsb; wsb += (size_t)N_EDGES * 4;
    P.rank       = (int*)wsb; wsb += (size_t)N_EDGES * 4;
    P.indeg      = (int*)wsb; wsb += (size_t)N_NODES * 4;
    P.row_start  = (int*)wsb; wsb += (size_t)(N_NODES + 2) * 4;
    P.bsum       = (int*)wsb; wsb += (size_t)NCHUNK * 4;

    const int TB = 256;
    int e_blocks  = (N_EDGES + TB - 1) / TB;
    int p0_blocks = (N_NODES + 8192 + 16384 + 16384 + N_PROTO * D + TB - 1) / TB;
    int fc_blocks = (N_EDGES + NC4 + TB - 1) / TB;

    kw_p0<<<p0_blocks, TB, 0, stream>>>(P);
    kw_count<<<e_blocks, TB, 0, stream>>>(P);
    kw_scan1<<<NCHUNK, SCAN_B, 0, stream>>>(P);
    kw_scan23<<<NCHUNK, SCAN_B, 0, stream>>>(P);
    kw_fillconv<<<fc_blocks, TB, 0, stream>>>(P);
    kw_agg64<<<GRP8, TB, 0, stream>>>(P);
    kw_gemm01<<<GEMM_TILES, TB, 0, stream>>>(P);     // agg0 -> bufA (hs1)
    kw_gather1<<<GRP8, TB, 0, stream>>>(P);          // bufA -> bufB (h2)
    kw_gemm2<<<GEMM_TILES, TB, 0, stream>>>(P);      // bufB -> bufA (hs2)
    kw_gather2<<<GRP8, TB, 0, stream>>>(P);          // bufA -> bufB (h3)
    kw_readout<<<N_GRAPHS, 512, 0, stream>>>(P);
}